// Round 18
// baseline (270.649 us; speedup 1.0000x reference)
//
#include <hip/hip_runtime.h>

typedef unsigned short u16;
typedef __attribute__((ext_vector_type(8))) __bf16 bf16x8;
typedef __attribute__((ext_vector_type(8))) unsigned short u16x8;
typedef __attribute__((ext_vector_type(4))) unsigned short u16x4;
typedef __attribute__((ext_vector_type(4))) float f32x4;

__device__ __forceinline__ float bf2f(u16 h) {
    return __uint_as_float(((unsigned int)h) << 16);
}
__device__ __forceinline__ u16 f2bf(float f) {
    unsigned int u = __float_as_uint(f);
    u += 0x7fffu + ((u >> 16) & 1u);   // round-to-nearest-even
    return (u16)(u >> 16);
}
union bfu { u16x8 u; bf16x8 b; };
__device__ __forceinline__ bf16x8 zero_bf16x8() {
    bfu z; z.u[0]=0;z.u[1]=0;z.u[2]=0;z.u[3]=0;z.u[4]=0;z.u[5]=0;z.u[6]=0;z.u[7]=0;
    return z.b;
}
__device__ __forceinline__ void gload_lds16(const void* g, void* l) {
    __builtin_amdgcn_global_load_lds(
        (const __attribute__((address_space(1))) unsigned int*)g,
        (__attribute__((address_space(3))) unsigned int*)l, 16, 0, 0);
}
__device__ __forceinline__ void store_out(u16* p, float v)  { *p = f2bf(v); }
__device__ __forceinline__ void store_out(float* p, float v){ *p = v; }

// ================= fused pre-pass (1 launch; R17 vectorized transpose) =====

__device__ __forceinline__ void do_cvt(
    const float* __restrict__ in, u16* __restrict__ out, int blk)
{
    int i = (blk * 256 + (int)threadIdx.x) * 8;
    float4 a = *(const float4*)(in + i);
    float4 b = *(const float4*)(in + i + 4);
    u16x8 o;
    o[0] = f2bf(a.x); o[1] = f2bf(a.y); o[2] = f2bf(a.z); o[3] = f2bf(a.w);
    o[4] = f2bf(b.x); o[5] = f2bf(b.y); o[6] = f2bf(b.z); o[7] = f2bf(b.w);
    *(u16x8*)(out + i) = o;
}

__device__ __forceinline__ void do_transpose64(
    const float* __restrict__ in, u16* __restrict__ out, int K, int F, int t)
{
    __shared__ u16 tt[64][68];
    int fb = t % (F >> 6), kb = t / (F >> 6);
    int f0 = fb << 6, k0 = kb << 6;
    int c  = threadIdx.x & 15;
    int r  = threadIdx.x >> 4;
#pragma unroll
    for (int p = 0; p < 4; ++p) {
        int row = p * 16 + r;
        float4 v = *(const float4*)(in + (size_t)(k0 + row) * F + f0 + c * 4);
        u16x4 w;
        w[0] = f2bf(v.x); w[1] = f2bf(v.y); w[2] = f2bf(v.z); w[3] = f2bf(v.w);
        *(u16x4*)&tt[row][c * 4] = w;
    }
    __syncthreads();
#pragma unroll
    for (int p = 0; p < 4; ++p) {
        int f = p * 16 + r;
        u16x4 w;
        w[0] = tt[c * 4 + 0][f];
        w[1] = tt[c * 4 + 1][f];
        w[2] = tt[c * 4 + 2][f];
        w[3] = tt[c * 4 + 3][f];
        *(u16x4*)(out + (size_t)(f0 + f) * K + k0 + c * 4) = w;
    }
}

__device__ __forceinline__ void do_prep_d(
    const float* __restrict__ d, u16* __restrict__ o, int K, int blk)
{
    int i = blk * 256 + (int)threadIdx.x;
    int r = i & 7;
    int k = (i >> 3) % K;
    int t = i / (K * 8);
    o[i] = f2bf(d[((size_t)k * 8 + r) * 8 + t]);
}

__device__ __forceinline__ void do_prep_u(
    const float* __restrict__ u, u16* __restrict__ o, int F, int blk)
{
    int i = blk * 256 + (int)threadIdx.x;
    int r = i & 7;
    int f = (i >> 3) % F;
    int t = i / (F * 8);
    o[i] = f2bf(u[((size_t)r * F + f) * 8 + t] * 2.0f);
}

__global__ __launch_bounds__(256) void prep_all(
    const float* x, const float* k0, const float* k1, const float* k2,
    const float* d0, const float* d1, const float* d2,
    const float* u0, const float* u1, const float* u2,
    u16* xb, u16* k0T, u16* k1T, u16* k2T,
    u16* dS0, u16* dS1, u16* dS2, u16* uS0, u16* uS1, u16* uS2)
{
    int b = blockIdx.x;
    if      (b < 4096) do_cvt(x, xb, b);
    else if (b < 4608) do_transpose64(k0, k0T, 1024, 2048, b - 4096);
    else if (b < 5632) do_transpose64(k1, k1T, 2048, 2048, b - 4608);
    else if (b < 6144) do_transpose64(k2, k2T, 2048, 1024, b - 5632);
    else if (b < 6400) do_prep_d(d0, dS0, 1024, b - 6144);
    else if (b < 6912) do_prep_d(d1, dS1, 2048, b - 6400);
    else if (b < 7424) do_prep_d(d2, dS2, 2048, b - 6912);
    else if (b < 7936) do_prep_u(u0, uS0, 2048, b - 7424);
    else if (b < 8448) do_prep_u(u1, uS1, 2048, b - 7936);
    else               do_prep_u(u2, uS2, 1024, b - 8448);
}

// ---------------- LoRA down-projection (layer 0 only now) ----------------
__global__ __launch_bounds__(256) void lora_down(
    const u16* __restrict__ H, const u16* __restrict__ dS,
    u16* __restrict__ Aout, int K)
{
    int gt   = blockIdx.x * 256 + threadIdx.x;
    int row  = gt >> 3;
    int oct  = gt & 7;
    int task = row >> 10;
    const u16* hrow = H  + (size_t)row * K;
    const u16* dt   = dS + (size_t)task * K * 8;
    float acc[8];
#pragma unroll
    for (int r = 0; r < 8; ++r) acc[r] = 0.f;
    int kpt  = K >> 3;
    int kbeg = oct * kpt;
    for (int kk = kbeg; kk < kbeg + kpt; kk += 8) {
        u16x8 h8 = *(const u16x8*)(hrow + kk);
#pragma unroll
        for (int j = 0; j < 8; ++j) {
            float hv = bf2f(h8[j]);
            u16x8 dv = *(const u16x8*)(dt + (size_t)(kk + j) * 8);
#pragma unroll
            for (int r = 0; r < 8; ++r)
                acc[r] += hv * bf2f(dv[r]);
        }
    }
#pragma unroll
    for (int r = 0; r < 8; ++r) {
        acc[r] += __shfl_xor(acc[r], 1);
        acc[r] += __shfl_xor(acc[r], 2);
        acc[r] += __shfl_xor(acc[r], 4);
    }
    if (oct == 0) {
        u16x8 o;
#pragma unroll
        for (int r = 0; r < 8; ++r) o[r] = f2bf(acc[r]);
        *(u16x8*)(Aout + (size_t)row * 8) = o;
    }
}

// ===== BMxBN 8-phase READ-AHEAD-1 GEMM + rank-8 LoRA epilogue ==============
// R18: + FUSED next-layer lora_down in producer epilogue (FUSE=1):
//   P[row][r] = sum_{col in tile} relu(h)*dSnext[col][r]; per-lane 4 FMA/val,
//   shfl_xor l15-reduce (stays in lg group = one row), LDS cross-wc sum in
//   dead sA, per-bn SLICE written with plain stores (no atomics). Consumer
//   (FSLICE=8) sums 8 f32 slices when loading the rank-8 A-operand.
// Core schedule unchanged from R13 (best measured; plateau across 7 variants).

#define WVMC do { if constexpr (SAL + SBL == 4) { \
                    asm volatile("s_waitcnt vmcnt(4)" ::: "memory"); \
                  } else if constexpr (SAL + SBL == 3) { \
                    asm volatile("s_waitcnt vmcnt(3)" ::: "memory"); \
                  } else { \
                    asm volatile("s_waitcnt vmcnt(2)" ::: "memory"); } } while (0)
#define WVMP do { if constexpr (SAL == 2) { \
                    asm volatile("s_waitcnt vmcnt(2)" ::: "memory"); \
                  } else { \
                    asm volatile("s_waitcnt vmcnt(1)" ::: "memory"); } } while (0)
#define WVM0  asm volatile("s_waitcnt vmcnt(0)" ::: "memory")
#define PHASE_END do { __builtin_amdgcn_sched_barrier(0); \
                       __builtin_amdgcn_s_barrier(); } while (0)

#define DS_A(c, mh) do { \
    _Pragma("unroll") for (int mm = 0; mm < NMH; ++mm) \
    _Pragma("unroll") for (int ks = 0; ks < 2; ++ks) \
        aF[mm][ks] = *(const bf16x8*)((const char*)&sA[c][0] + \
                       arowb + ((mh)*NMH+mm)*4096 + (ks ? cb1 : cb0)); } while (0)

#define DS_B(c, nh, bset) do { \
    _Pragma("unroll") for (int nn = 0; nn < NBH; ++nn) \
    _Pragma("unroll") for (int ks = 0; ks < 2; ++ks) \
        bset[nn][ks] = *(const bf16x8*)((const char*)&sB[c][0] + \
                       browb + ((nh)*NBH+nn)*8192 + (ks ? cb1 : cb0)); } while (0)

#define MFMAQ(mh, nh, bset) do { \
    _Pragma("unroll") for (int ks = 0; ks < 2; ++ks) \
    _Pragma("unroll") for (int mm = 0; mm < NMH; ++mm) \
    _Pragma("unroll") for (int nn = 0; nn < NBH; ++nn) \
        acc[(mh)*NMH+mm][(nh)*NBH+nn] = __builtin_amdgcn_mfma_f32_16x16x32_bf16( \
            aF[mm][ks], bset[nn][ks], acc[(mh)*NMH+mm][(nh)*NBH+nn], 0, 0, 0); } while (0)

#define STAGE_A(c, h, kt) do { \
    _Pragma("unroll") for (int s = 0; s < SAL; ++s) \
        gload_lds16((const char*)A + (size_t)(unsigned)(aBase + \
                      ((h)*BMH + s*64)*(K*2) + (kt)*128), \
                    (char*)&sA[c][0] + (h)*(BMH*128) + s*8192 + tdst); } while (0)

#define STAGE_B(c, h, kt) do { \
    _Pragma("unroll") for (int s = 0; s < SBL; ++s) \
        gload_lds16((const char*)BT + (size_t)(unsigned)(bBase + \
                      ((h)*BNH + s*64)*(K*2) + (kt)*128), \
                    (char*)&sB[c][0] + (h)*(BNH*128) + s*8192 + tdst); } while (0)

template<int RELU, int BM, int BN, int WPEU, int FSLICE, int FUSE, typename OUT_T>
__global__ __launch_bounds__(512, WPEU) void gemm_lora8(
    const u16* __restrict__ A, const u16* __restrict__ BT,
    const void* __restrict__ ALR, const u16* __restrict__ US,
    const float* __restrict__ bias, OUT_T* __restrict__ C,
    const u16* __restrict__ DSN, float* __restrict__ ABOUT,
    int N, int K)
{
    constexpr int SAL = BM / 128;
    constexpr int SBL = BN / 128;
    constexpr int NMH = BM / 64;
    constexpr int NMB = BM / 32;
    constexpr int NBH = BN / 128;
    constexpr int NBN = BN / 64;
    constexpr int BMH = BM / 2;
    constexpr int BNH = BN / 2;

    __shared__ __align__(16) u16 sA[2][BM * 64];
    __shared__ __align__(16) u16 sB[2][BN * 64];

    const int tid  = threadIdx.x;
    const int lane = tid & 63;
    const int wave = tid >> 6;
    const int wr   = wave >> 2;
    const int wc   = wave & 3;
    const int l15  = lane & 15;
    const int lg   = lane >> 4;

    // bijective XCD swizzle (m204)
    const int nwg = gridDim.x;
    const int orig = blockIdx.x;
    const int q = nwg >> 3, r = nwg & 7;
    const int x = orig & 7, o = orig >> 3;
    const int wg = (x < r ? x * (q + 1) : r * (q + 1) + (x - r) * q) + o;
    const int nbn  = N / BN;
    const int bm   = wg / nbn;
    const int bn   = wg % nbn;
    const int brow = bm * BM;
    const int bcol = bn * BN;
    const int task = brow >> 10;

    const int trow = tid >> 3;
    const int tkc  = (tid & 7) ^ (trow & 7);
    const int tdst = tid * 16;
    const int aBase = (brow + trow) * (K * 2) + tkc * 16;
    const int bBase = (bcol + trow) * (K * 2) + tkc * 16;

    const int rp    = l15 & 7;
    const int cb0   = ((lg ^ (rp & 3)) << 4) | ((rp & 4) << 4);
    const int cb1   = cb0 ^ 64;
    const int arowb = (wr * 16 + l15) * 128;
    const int browb = (wc * 16 + l15) * 128;

    f32x4 acc[NMB][NBN];
    const f32x4 zf = {0.f, 0.f, 0.f, 0.f};
#pragma unroll
    for (int m = 0; m < NMB; ++m)
#pragma unroll
        for (int n = 0; n < NBN; ++n) acc[m][n] = zf;

    bf16x8 aF[NMH][2], bF0[NBH][2], bF1[NBH][2];

    STAGE_A(0, 0, 0); STAGE_B(0, 0, 0); STAGE_A(0, 1, 0); STAGE_B(0, 1, 0);
    STAGE_A(1, 0, 1); STAGE_B(1, 0, 1);
    WVMC;
    PHASE_END;
    DS_A(0, 0); DS_B(0, 0, bF0);

    const int iters = K >> 7;
#pragma unroll 1
    for (int i = 0; i < iters; ++i) {
        const int t1 = 2 * i + 1, t2 = 2 * i + 2, t3 = 2 * i + 3;
        const bool nl = (i + 1 < iters);

        STAGE_A(1, 1, t1);
        MFMAQ(0, 0, bF0);
        DS_B(0, 1, bF1);
        PHASE_END;
        STAGE_B(1, 1, t1);
        MFMAQ(0, 1, bF1);
        DS_A(0, 1);
        PHASE_END;
        if (nl) STAGE_A(0, 0, t2);
        MFMAQ(1, 0, bF0);
        if (nl) { WVMP; } else { WVM0; }
        PHASE_END;
        if (nl) STAGE_B(0, 0, t2);
        MFMAQ(1, 1, bF1);
        DS_A(1, 0); DS_B(1, 0, bF0);
        PHASE_END;
        if (nl) STAGE_A(0, 1, t2);
        MFMAQ(0, 0, bF0);
        DS_B(1, 1, bF1);
        PHASE_END;
        if (nl) STAGE_B(0, 1, t2);
        MFMAQ(0, 1, bF1);
        DS_A(1, 1);
        PHASE_END;
        if (nl) STAGE_A(1, 0, t3);
        MFMAQ(1, 0, bF0);
        if (nl) { WVMP; }
        PHASE_END;
        if (nl) STAGE_B(1, 0, t3);
        MFMAQ(1, 1, bF1);
        if (nl) { DS_A(0, 0); DS_B(0, 0, bF0); }
        PHASE_END;
    }

    // rank-8 LoRA delta: A-operand from u16 buffer (FSLICE=0) or summed f32
    // slices (FSLICE=8, written by producer gemm's fused epilogue).
    bf16x8 z8 = zero_bf16x8();
    bf16x8 bU[NBN];
#pragma unroll
    for (int n = 0; n < NBN; ++n) {
        int col = bcol + n * 64 + wc * 16 + l15;
        bU[n] = (lg == 0) ? *(const bf16x8*)(US + ((size_t)task * N + col) * 8) : z8;
    }
#pragma unroll
    for (int m = 0; m < NMB; ++m) {
        int row = brow + m * 32 + wr * 16 + l15;
        bf16x8 aL;
        if (lg == 0) {
            if constexpr (FSLICE == 0) {
                aL = *(const bf16x8*)((const u16*)ALR + (size_t)row * 8);
            } else {
                f32x4 lo = zf, hi = zf;
#pragma unroll
                for (int s = 0; s < FSLICE; ++s) {
                    const float* sp = (const float*)ALR + (size_t)s * 8192 * 8
                                      + (size_t)row * 8;
                    lo += *(const f32x4*)sp;
                    hi += *(const f32x4*)(sp + 4);
                }
                bfu t;
#pragma unroll
                for (int j = 0; j < 4; ++j) { t.u[j] = f2bf(lo[j]); t.u[4+j] = f2bf(hi[j]); }
                aL = t.b;
            }
        } else aL = z8;
#pragma unroll
        for (int n = 0; n < NBN; ++n)
            acc[m][n] = __builtin_amdgcn_mfma_f32_16x16x32_bf16(
                aL, bU[n], acc[m][n], 0, 0, 0);
    }

    if constexpr (FUSE) {
        // fused next-layer lora_down partials + bias/ReLU + C store
        float dSf[NBN][8];
#pragma unroll
        for (int n = 0; n < NBN; ++n) {
            int col = bcol + n * 64 + wc * 16 + l15;
            u16x8 dv = *(const u16x8*)(DSN + ((size_t)task * N + col) * 8);
#pragma unroll
            for (int rr = 0; rr < 8; ++rr) dSf[n][rr] = bf2f(dv[rr]);
        }
        float* ldsP = (float*)&sA[0][0];   // [wc][256][8] f32 = 32 KiB
#pragma unroll
        for (int m = 0; m < NMB; ++m) {
#pragma unroll
            for (int rr = 0; rr < 4; ++rr) {
                int rl  = m * 32 + wr * 16 + lg * 4 + rr;
                int row = brow + rl;
                float p[8];
#pragma unroll
                for (int j = 0; j < 8; ++j) p[j] = 0.f;
#pragma unroll
                for (int n = 0; n < NBN; ++n) {
                    int col  = bcol + n * 64 + wc * 16 + l15;
                    float v = acc[m][n][rr] + bias[col];
                    if (RELU) v = fmaxf(v, 0.0f);
                    store_out(&C[(size_t)row * N + col], v);
#pragma unroll
                    for (int j = 0; j < 8; ++j) p[j] += v * dSf[n][j];
                }
#pragma unroll
                for (int s = 1; s < 16; s <<= 1)
#pragma unroll
                    for (int j = 0; j < 8; ++j) p[j] += __shfl_xor(p[j], s);
                if (l15 == 0) {
                    f32x4 w0 = {p[0], p[1], p[2], p[3]};
                    f32x4 w1 = {p[4], p[5], p[6], p[7]};
                    *(f32x4*)&ldsP[(wc * 256 + rl) * 8]     = w0;
                    *(f32x4*)&ldsP[(wc * 256 + rl) * 8 + 4] = w1;
                }
            }
        }
        __syncthreads();
        // cross-wc sum -> per-bn slice (plain stores, summed by consumer)
        for (int i = tid; i < 2048; i += 512) {
            float s = ldsP[i] + ldsP[2048 + i] + ldsP[4096 + i] + ldsP[6144 + i];
            ABOUT[(size_t)bn * (8192 * 8) + (size_t)brow * 8 + i] = s;
        }
    } else {
#pragma unroll
        for (int n = 0; n < NBN; ++n) {
            int col  = bcol + n * 64 + wc * 16 + l15;
            float bv = bias[col];
#pragma unroll
            for (int m = 0; m < NMB; ++m) {
                int row0 = brow + m * 32 + wr * 16 + lg * 4;
#pragma unroll
                for (int rr = 0; rr < 4; ++rr) {
                    float v = acc[m][n][rr] + bv;
                    if (RELU) v = fmaxf(v, 0.0f);
                    store_out(&C[(size_t)(row0 + rr) * N + col], v);
                }
            }
        }
    }
}

// ---------------- launch ----------------

extern "C" void kernel_launch(void* const* d_in, const int* in_sizes, int n_in,
                              void* d_out, int out_size, void* d_ws, size_t ws_size,
                              hipStream_t stream) {
    const float* x  = (const float*)d_in[0];
    const float* k0 = (const float*)d_in[1];
    const float* b0 = (const float*)d_in[2];
    const float* d0 = (const float*)d_in[3];
    const float* u0 = (const float*)d_in[4];
    const float* k1 = (const float*)d_in[5];
    const float* b1 = (const float*)d_in[6];
    const float* d1 = (const float*)d_in[7];
    const float* u1 = (const float*)d_in[8];
    const float* k2 = (const float*)d_in[9];
    const float* b2 = (const float*)d_in[10];
    const float* d2 = (const float*)d_in[11];
    const float* u2 = (const float*)d_in[12];

    const int T = 8, B = 1024, D = 1024, H1 = 2048, H2 = 2048, H3 = 1024;
    const int M = T * B;

    u16* w = (u16*)d_ws;
    size_t off = 0;
    u16* xb  = w + off; off += (size_t)M * D;
    u16* k0T = w + off; off += (size_t)H1 * D;
    u16* k1T = w + off; off += (size_t)H2 * H1;
    u16* k2T = w + off; off += (size_t)H3 * H2;
    u16* dS0 = w + off; off += (size_t)T * D * 8;
    u16* dS1 = w + off; off += (size_t)T * H1 * 8;
    u16* dS2 = w + off; off += (size_t)T * H2 * 8;
    u16* uS0 = w + off; off += (size_t)T * H1 * 8;
    u16* uS1 = w + off; off += (size_t)T * H2 * 8;
    u16* uS2 = w + off; off += (size_t)T * H3 * 8;
    u16* h1  = w + off; off += (size_t)M * H1;
    u16* h2  = w + off; off += (size_t)M * H2;
    u16* Ab  = w + off; off += (size_t)M * 8;
    float* AbP1 = (float*)(w + off); off += (size_t)8 * M * 8 * 2;  // 8 slices f32
    float* AbP2 = (float*)(w + off); off += (size_t)8 * M * 8 * 2;
    (void)ws_size; (void)in_sizes; (void)n_in; (void)out_size;

    prep_all<<<8704, 256, 0, stream>>>(
        x, k0, k1, k2, d0, d1, d2, u0, u1, u2,
        xb, k0T, k1T, k2T, dS0, dS1, dS2, uS0, uS1, uS2);

    // layer 0: lora0 (u16 Ab) + gemm fused with layer-1 lora_down (-> AbP1)
    lora_down<<<(M * 8) / 256, 256, 0, stream>>>(xb, dS0, Ab, D);
    gemm_lora8<1, 256, 256, 2, 0, 1, u16>
        <<<(M / 256) * (H1 / 256), 512, 0, stream>>>(
        xb, k0T, Ab, uS0, b0, h1, dS1, AbP1, H1, D);
    // layer 1: consumes AbP1 slices; fused with layer-2 lora_down (-> AbP2)
    gemm_lora8<1, 256, 256, 2, 8, 1, u16>
        <<<(M / 256) * (H2 / 256), 512, 0, stream>>>(
        h1, k1T, AbP1, uS1, b1, h2, dS2, AbP2, H2, H1);
    // layer 2: consumes AbP2 slices; no fusion, fp32 out, (128,128) 2-blk/CU
    gemm_lora8<0, 128, 128, 4, 8, 0, float>
        <<<(M / 128) * (H3 / 128), 512, 0, stream>>>(
        h2, k2T, AbP2, uS2, b2, (float*)d_out, (const u16*)nullptr,
        (float*)nullptr, H3, H2);
}

// Round 19
// 258.237 us; speedup vs baseline: 1.0481x; 1.0481x over previous
//
#include <hip/hip_runtime.h>

typedef unsigned short u16;
typedef __attribute__((ext_vector_type(8))) __bf16 bf16x8;
typedef __attribute__((ext_vector_type(8))) unsigned short u16x8;
typedef __attribute__((ext_vector_type(4))) unsigned short u16x4;
typedef __attribute__((ext_vector_type(4))) float f32x4;

__device__ __forceinline__ float bf2f(u16 h) {
    return __uint_as_float(((unsigned int)h) << 16);
}
__device__ __forceinline__ u16 f2bf(float f) {
    unsigned int u = __float_as_uint(f);
    u += 0x7fffu + ((u >> 16) & 1u);   // round-to-nearest-even
    return (u16)(u >> 16);
}
__device__ __forceinline__ bf16x8 zero_bf16x8() {
    union { unsigned int u[4]; bf16x8 v; } z;
    z.u[0] = z.u[1] = z.u[2] = z.u[3] = 0u;
    return z.v;
}
__device__ __forceinline__ void gload_lds16(const void* g, void* l) {
    __builtin_amdgcn_global_load_lds(
        (const __attribute__((address_space(1))) unsigned int*)g,
        (__attribute__((address_space(3))) unsigned int*)l, 16, 0, 0);
}
__device__ __forceinline__ void store_out(u16* p, float v)  { *p = f2bf(v); }
__device__ __forceinline__ void store_out(float* p, float v){ *p = v; }

// ================= fused pre-pass (1 launch; R17 vectorized transpose) =====

__device__ __forceinline__ void do_cvt(
    const float* __restrict__ in, u16* __restrict__ out, int blk)
{
    int i = (blk * 256 + (int)threadIdx.x) * 8;
    float4 a = *(const float4*)(in + i);
    float4 b = *(const float4*)(in + i + 4);
    u16x8 o;
    o[0] = f2bf(a.x); o[1] = f2bf(a.y); o[2] = f2bf(a.z); o[3] = f2bf(a.w);
    o[4] = f2bf(b.x); o[5] = f2bf(b.y); o[6] = f2bf(b.z); o[7] = f2bf(b.w);
    *(u16x8*)(out + i) = o;
}

__device__ __forceinline__ void do_transpose64(
    const float* __restrict__ in, u16* __restrict__ out, int K, int F, int t)
{
    __shared__ u16 tt[64][68];
    int fb = t % (F >> 6), kb = t / (F >> 6);
    int f0 = fb << 6, k0 = kb << 6;
    int c  = threadIdx.x & 15;
    int r  = threadIdx.x >> 4;
#pragma unroll
    for (int p = 0; p < 4; ++p) {
        int row = p * 16 + r;
        float4 v = *(const float4*)(in + (size_t)(k0 + row) * F + f0 + c * 4);
        u16x4 w;
        w[0] = f2bf(v.x); w[1] = f2bf(v.y); w[2] = f2bf(v.z); w[3] = f2bf(v.w);
        *(u16x4*)&tt[row][c * 4] = w;
    }
    __syncthreads();
#pragma unroll
    for (int p = 0; p < 4; ++p) {
        int f = p * 16 + r;
        u16x4 w;
        w[0] = tt[c * 4 + 0][f];
        w[1] = tt[c * 4 + 1][f];
        w[2] = tt[c * 4 + 2][f];
        w[3] = tt[c * 4 + 3][f];
        *(u16x4*)(out + (size_t)(f0 + f) * K + k0 + c * 4) = w;
    }
}

__device__ __forceinline__ void do_prep_d(
    const float* __restrict__ d, u16* __restrict__ o, int K, int blk)
{
    int i = blk * 256 + (int)threadIdx.x;
    int r = i & 7;
    int k = (i >> 3) % K;
    int t = i / (K * 8);
    o[i] = f2bf(d[((size_t)k * 8 + r) * 8 + t]);
}

__device__ __forceinline__ void do_prep_u(
    const float* __restrict__ u, u16* __restrict__ o, int F, int blk)
{
    int i = blk * 256 + (int)threadIdx.x;
    int r = i & 7;
    int f = (i >> 3) % F;
    int t = i / (F * 8);
    o[i] = f2bf(u[((size_t)r * F + f) * 8 + t] * 2.0f);
}

__global__ __launch_bounds__(256) void prep_all(
    const float* x, const float* k0, const float* k1, const float* k2,
    const float* d0, const float* d1, const float* d2,
    const float* u0, const float* u1, const float* u2,
    u16* xb, u16* k0T, u16* k1T, u16* k2T,
    u16* dS0, u16* dS1, u16* dS2, u16* uS0, u16* uS1, u16* uS2)
{
    int b = blockIdx.x;
    if      (b < 4096) do_cvt(x, xb, b);
    else if (b < 4608) do_transpose64(k0, k0T, 1024, 2048, b - 4096);
    else if (b < 5632) do_transpose64(k1, k1T, 2048, 2048, b - 4608);
    else if (b < 6144) do_transpose64(k2, k2T, 2048, 1024, b - 5632);
    else if (b < 6400) do_prep_d(d0, dS0, 1024, b - 6144);
    else if (b < 6912) do_prep_d(d1, dS1, 2048, b - 6400);
    else if (b < 7424) do_prep_d(d2, dS2, 2048, b - 6912);
    else if (b < 7936) do_prep_u(u0, uS0, 2048, b - 7424);
    else if (b < 8448) do_prep_u(u1, uS1, 2048, b - 7936);
    else               do_prep_u(u2, uS2, 1024, b - 8448);
}

// ---------------- LoRA down-projection (all 3 layers) ----------------
__global__ __launch_bounds__(256) void lora_down(
    const u16* __restrict__ H, const u16* __restrict__ dS,
    u16* __restrict__ Aout, int K)
{
    int gt   = blockIdx.x * 256 + threadIdx.x;
    int row  = gt >> 3;
    int oct  = gt & 7;
    int task = row >> 10;
    const u16* hrow = H  + (size_t)row * K;
    const u16* dt   = dS + (size_t)task * K * 8;
    float acc[8];
#pragma unroll
    for (int r = 0; r < 8; ++r) acc[r] = 0.f;
    int kpt  = K >> 3;
    int kbeg = oct * kpt;
    for (int kk = kbeg; kk < kbeg + kpt; kk += 8) {
        u16x8 h8 = *(const u16x8*)(hrow + kk);
#pragma unroll
        for (int j = 0; j < 8; ++j) {
            float hv = bf2f(h8[j]);
            u16x8 dv = *(const u16x8*)(dt + (size_t)(kk + j) * 8);
#pragma unroll
            for (int r = 0; r < 8; ++r)
                acc[r] += hv * bf2f(dv[r]);
        }
    }
#pragma unroll
    for (int r = 0; r < 8; ++r) {
        acc[r] += __shfl_xor(acc[r], 1);
        acc[r] += __shfl_xor(acc[r], 2);
        acc[r] += __shfl_xor(acc[r], 4);
    }
    if (oct == 0) {
        u16x8 o;
#pragma unroll
        for (int r = 0; r < 8; ++r) o[r] = f2bf(acc[r]);
        *(u16x8*)(Aout + (size_t)row * 8) = o;
    }
}

// ===== BMxBN 8-phase READ-AHEAD-1 GEMM + rank-8 LoRA epilogue (R13/R17) ====
// FINAL measured-best configuration (258.6 us total). Session ledger:
//  - schedule plateau ~10.3K cyc/iter across 7 variants (R5-R16); MfmaUtil
//    ~41-42% is this structure's floor at 1 block/CU lockstep.
//  - R18's epilogue fusion of next-layer lora_down regressed 2x (cross-tile
//    reduce = ~1K VALU ops/thread) — reverted. Fusion only pays when the
//    fused work is O(accumulator) cheap.
// Swizzle: chunk kc of row r at slot kc^(r&7) (0 bank conflicts since R3);
// read-ahead-1 same-register; counted vmcnt at P2/P6 (publish shift); one
// sched_barrier+s_barrier per phase. Hazard maps: R12 derivation.

#define WVMC do { if constexpr (SAL + SBL == 4) { \
                    asm volatile("s_waitcnt vmcnt(4)" ::: "memory"); \
                  } else if constexpr (SAL + SBL == 3) { \
                    asm volatile("s_waitcnt vmcnt(3)" ::: "memory"); \
                  } else { \
                    asm volatile("s_waitcnt vmcnt(2)" ::: "memory"); } } while (0)
#define WVMP do { if constexpr (SAL == 2) { \
                    asm volatile("s_waitcnt vmcnt(2)" ::: "memory"); \
                  } else { \
                    asm volatile("s_waitcnt vmcnt(1)" ::: "memory"); } } while (0)
#define WVM0  asm volatile("s_waitcnt vmcnt(0)" ::: "memory")
#define PHASE_END do { __builtin_amdgcn_sched_barrier(0); \
                       __builtin_amdgcn_s_barrier(); } while (0)

#define DS_A(c, mh) do { \
    _Pragma("unroll") for (int mm = 0; mm < NMH; ++mm) \
    _Pragma("unroll") for (int ks = 0; ks < 2; ++ks) \
        aF[mm][ks] = *(const bf16x8*)((const char*)&sA[c][0] + \
                       arowb + ((mh)*NMH+mm)*4096 + (ks ? cb1 : cb0)); } while (0)

#define DS_B(c, nh, bset) do { \
    _Pragma("unroll") for (int nn = 0; nn < NBH; ++nn) \
    _Pragma("unroll") for (int ks = 0; ks < 2; ++ks) \
        bset[nn][ks] = *(const bf16x8*)((const char*)&sB[c][0] + \
                       browb + ((nh)*NBH+nn)*8192 + (ks ? cb1 : cb0)); } while (0)

#define MFMAQ(mh, nh, bset) do { \
    _Pragma("unroll") for (int ks = 0; ks < 2; ++ks) \
    _Pragma("unroll") for (int mm = 0; mm < NMH; ++mm) \
    _Pragma("unroll") for (int nn = 0; nn < NBH; ++nn) \
        acc[(mh)*NMH+mm][(nh)*NBH+nn] = __builtin_amdgcn_mfma_f32_16x16x32_bf16( \
            aF[mm][ks], bset[nn][ks], acc[(mh)*NMH+mm][(nh)*NBH+nn], 0, 0, 0); } while (0)

#define STAGE_A(c, h, kt) do { \
    _Pragma("unroll") for (int s = 0; s < SAL; ++s) \
        gload_lds16((const char*)A + (size_t)(unsigned)(aBase + \
                      ((h)*BMH + s*64)*(K*2) + (kt)*128), \
                    (char*)&sA[c][0] + (h)*(BMH*128) + s*8192 + tdst); } while (0)

#define STAGE_B(c, h, kt) do { \
    _Pragma("unroll") for (int s = 0; s < SBL; ++s) \
        gload_lds16((const char*)BT + (size_t)(unsigned)(bBase + \
                      ((h)*BNH + s*64)*(K*2) + (kt)*128), \
                    (char*)&sB[c][0] + (h)*(BNH*128) + s*8192 + tdst); } while (0)

template<int RELU, int BM, int BN, int WPEU, typename OUT_T>
__global__ __launch_bounds__(512, WPEU) void gemm_lora8(
    const u16* __restrict__ A, const u16* __restrict__ BT,
    const u16* __restrict__ ALR, const u16* __restrict__ US,
    const float* __restrict__ bias, OUT_T* __restrict__ C,
    int N, int K)
{
    constexpr int SAL = BM / 128;
    constexpr int SBL = BN / 128;
    constexpr int NMH = BM / 64;
    constexpr int NMB = BM / 32;
    constexpr int NBH = BN / 128;
    constexpr int NBN = BN / 64;
    constexpr int BMH = BM / 2;
    constexpr int BNH = BN / 2;

    __shared__ __align__(16) u16 sA[2][BM * 64];
    __shared__ __align__(16) u16 sB[2][BN * 64];

    const int tid  = threadIdx.x;
    const int lane = tid & 63;
    const int wave = tid >> 6;
    const int wr   = wave >> 2;
    const int wc   = wave & 3;
    const int l15  = lane & 15;
    const int lg   = lane >> 4;

    // bijective XCD swizzle (m204)
    const int nwg = gridDim.x;
    const int orig = blockIdx.x;
    const int q = nwg >> 3, r = nwg & 7;
    const int x = orig & 7, o = orig >> 3;
    const int wg = (x < r ? x * (q + 1) : r * (q + 1) + (x - r) * q) + o;
    const int nbn  = N / BN;
    const int bm   = wg / nbn;
    const int bn   = wg % nbn;
    const int brow = bm * BM;
    const int bcol = bn * BN;
    const int task = brow >> 10;

    const int trow = tid >> 3;
    const int tkc  = (tid & 7) ^ (trow & 7);
    const int tdst = tid * 16;
    const int aBase = (brow + trow) * (K * 2) + tkc * 16;
    const int bBase = (bcol + trow) * (K * 2) + tkc * 16;

    const int rp    = l15 & 7;
    const int cb0   = ((lg ^ (rp & 3)) << 4) | ((rp & 4) << 4);
    const int cb1   = cb0 ^ 64;
    const int arowb = (wr * 16 + l15) * 128;
    const int browb = (wc * 16 + l15) * 128;

    f32x4 acc[NMB][NBN];
    const f32x4 zf = {0.f, 0.f, 0.f, 0.f};
#pragma unroll
    for (int m = 0; m < NMB; ++m)
#pragma unroll
        for (int n = 0; n < NBN; ++n) acc[m][n] = zf;

    bf16x8 aF[NMH][2], bF0[NBH][2], bF1[NBH][2];

    STAGE_A(0, 0, 0); STAGE_B(0, 0, 0); STAGE_A(0, 1, 0); STAGE_B(0, 1, 0);
    STAGE_A(1, 0, 1); STAGE_B(1, 0, 1);
    WVMC;
    PHASE_END;
    DS_A(0, 0); DS_B(0, 0, bF0);

    const int iters = K >> 7;
#pragma unroll 1
    for (int i = 0; i < iters; ++i) {
        const int t1 = 2 * i + 1, t2 = 2 * i + 2, t3 = 2 * i + 3;
        const bool nl = (i + 1 < iters);

        STAGE_A(1, 1, t1);
        MFMAQ(0, 0, bF0);
        DS_B(0, 1, bF1);
        PHASE_END;
        STAGE_B(1, 1, t1);
        MFMAQ(0, 1, bF1);
        DS_A(0, 1);
        PHASE_END;
        if (nl) STAGE_A(0, 0, t2);
        MFMAQ(1, 0, bF0);
        if (nl) { WVMP; } else { WVM0; }
        PHASE_END;
        if (nl) STAGE_B(0, 0, t2);
        MFMAQ(1, 1, bF1);
        DS_A(1, 0); DS_B(1, 0, bF0);
        PHASE_END;
        if (nl) STAGE_A(0, 1, t2);
        MFMAQ(0, 0, bF0);
        DS_B(1, 1, bF1);
        PHASE_END;
        if (nl) STAGE_B(0, 1, t2);
        MFMAQ(0, 1, bF1);
        DS_A(1, 1);
        PHASE_END;
        if (nl) STAGE_A(1, 0, t3);
        MFMAQ(1, 0, bF0);
        if (nl) { WVMP; }
        PHASE_END;
        if (nl) STAGE_B(1, 0, t3);
        MFMAQ(1, 1, bF1);
        if (nl) { DS_A(0, 0); DS_B(0, 0, bF0); }
        PHASE_END;
    }

    bf16x8 z8 = zero_bf16x8();
    bf16x8 bU[NBN];
#pragma unroll
    for (int n = 0; n < NBN; ++n) {
        int col = bcol + n * 64 + wc * 16 + l15;
        bU[n] = (lg == 0) ? *(const bf16x8*)(US + ((size_t)task * N + col) * 8) : z8;
    }
#pragma unroll
    for (int m = 0; m < NMB; ++m) {
        int row = brow + m * 32 + wr * 16 + l15;
        bf16x8 aL = (lg == 0) ? *(const bf16x8*)(ALR + (size_t)row * 8) : z8;
#pragma unroll
        for (int n = 0; n < NBN; ++n)
            acc[m][n] = __builtin_amdgcn_mfma_f32_16x16x32_bf16(
                aL, bU[n], acc[m][n], 0, 0, 0);
    }

#pragma unroll
    for (int n = 0; n < NBN; ++n) {
        int col  = bcol + n * 64 + wc * 16 + l15;
        float bv = bias[col];
#pragma unroll
        for (int m = 0; m < NMB; ++m) {
            int row0 = brow + m * 32 + wr * 16 + lg * 4;
#pragma unroll
            for (int rr = 0; rr < 4; ++rr) {
                float v = acc[m][n][rr] + bv;
                if (RELU) v = fmaxf(v, 0.0f);
                store_out(&C[(size_t)(row0 + rr) * N + col], v);
            }
        }
    }
}

// ---------------- launch ----------------

extern "C" void kernel_launch(void* const* d_in, const int* in_sizes, int n_in,
                              void* d_out, int out_size, void* d_ws, size_t ws_size,
                              hipStream_t stream) {
    const float* x  = (const float*)d_in[0];
    const float* k0 = (const float*)d_in[1];
    const float* b0 = (const float*)d_in[2];
    const float* d0 = (const float*)d_in[3];
    const float* u0 = (const float*)d_in[4];
    const float* k1 = (const float*)d_in[5];
    const float* b1 = (const float*)d_in[6];
    const float* d1 = (const float*)d_in[7];
    const float* u1 = (const float*)d_in[8];
    const float* k2 = (const float*)d_in[9];
    const float* b2 = (const float*)d_in[10];
    const float* d2 = (const float*)d_in[11];
    const float* u2 = (const float*)d_in[12];

    const int T = 8, B = 1024, D = 1024, H1 = 2048, H2 = 2048, H3 = 1024;
    const int M = T * B;

    u16* w = (u16*)d_ws;
    size_t off = 0;
    u16* xb  = w + off; off += (size_t)M * D;
    u16* k0T = w + off; off += (size_t)H1 * D;
    u16* k1T = w + off; off += (size_t)H2 * H1;
    u16* k2T = w + off; off += (size_t)H3 * H2;
    u16* dS0 = w + off; off += (size_t)T * D * 8;
    u16* dS1 = w + off; off += (size_t)T * H1 * 8;
    u16* dS2 = w + off; off += (size_t)T * H2 * 8;
    u16* uS0 = w + off; off += (size_t)T * H1 * 8;
    u16* uS1 = w + off; off += (size_t)T * H2 * 8;
    u16* uS2 = w + off; off += (size_t)T * H3 * 8;
    u16* h1  = w + off; off += (size_t)M * H1;
    u16* h2  = w + off; off += (size_t)M * H2;
    u16* Ab  = w + off; off += (size_t)M * 8;
    (void)ws_size; (void)in_sizes; (void)n_in; (void)out_size;

    prep_all<<<8704, 256, 0, stream>>>(
        x, k0, k1, k2, d0, d1, d2, u0, u1, u2,
        xb, k0T, k1T, k2T, dS0, dS1, dS2, uS0, uS1, uS2);

    // layer 0 (BM=256,BN=256: 256 blocks, 1 block/CU)
    lora_down<<<(M * 8) / 256, 256, 0, stream>>>(xb, dS0, Ab, D);
    gemm_lora8<1, 256, 256, 2, u16><<<(M / 256) * (H1 / 256), 512, 0, stream>>>(
        xb, k0T, Ab, uS0, b0, h1, H1, D);
    // layer 1 (BM=256,BN=256: 256 blocks, 1 block/CU)
    lora_down<<<(M * 8) / 256, 256, 0, stream>>>(h1, dS1, Ab, H1);
    gemm_lora8<1, 256, 256, 2, u16><<<(M / 256) * (H2 / 256), 512, 0, stream>>>(
        h1, k1T, Ab, uS1, b1, h2, H2, H1);
    // layer 2 (no relu, fp32 out; BM=BN=128: 512 blocks, 2 blocks/CU)
    lora_down<<<(M * 8) / 256, 256, 0, stream>>>(h2, dS2, Ab, H2);
    gemm_lora8<0, 128, 128, 4, float><<<(M / 128) * (H3 / 128), 512, 0, stream>>>(
        h2, k2T, Ab, uS2, b2, (float*)d_out, H3, H2);
}